// Round 8
// baseline (4000.748 us; speedup 1.0000x reference)
//
#include <hip/hip_runtime.h>
#include <hip/hip_bf16.h>
#include <hip/hip_fp16.h>

// ============================================================================
// 2-layer LSTM (TF BasicLSTMCell, forget_bias=1), B=32, T=2048, D=H=256.
// R13: consumer-side L2 fast path via PLAIN VOLATILE LOADS (no asm, no RMW).
//   Ledger: R6 reg-pin null; R7 on-chain-dot halved null; R12 publish-side
//   atomicExch null => visibility is prompt, Lambda is CONSUMER probe RT
//   (agent load -> MALL ~900cy + quantization ~= 2500cy of the 3700cy step).
//   R8/R9 (asm sc0 probe) crashed; R10 (CAS probe) dirtied lines (+28%).
//   The remaining HIP-expressible L2 probe: a plain volatile load walks
//   L1->L2, and the same-XCD producer's plain store lands in that SHARED L2
//   (~200cy). Staleness control:
//     * H1T is write-once -> consumer's first touch of each line happens
//       ~1 tail AFTER publish (B-poll timing) -> first L1 fill is fresh.
//     * every round also issues 1 agent-scope probe (R7-proven) ->
//       guaranteed progress at worst-R7 speed if placement/timing fail.
//     * H2R ring deepened 4 -> 64 slots (2MB) so reused lines cycle out of
//       the consumer's 32KB L1 between touches (poll traffic ~512B/step).
//   Publish = plain volatile store (fast L2 carrier, write-through L1) +
//   agent atomicExch (MALL copy, R12-proven). Dual-publish ran safely in R10.
//   Unchanged from R7/R12: 256 WGs = 2L x 4slice x 32batch, 512 thr; A/B
//   split dot; x(t+1) prefetch; tagged words (t<<16|f16, poison-safe);
//   wave0 own-slice LDS self-stage; H1 write-once trace; prep/Wrec; detect.
// ============================================================================

typedef _Float16 half_t;
typedef __attribute__((ext_vector_type(2))) _Float16 h2v;

static __device__ __forceinline__ float bf2f(unsigned short u) {
  union { unsigned u; float f; } v; v.u = ((unsigned)u) << 16; return v.f;
}
static __device__ __forceinline__ unsigned short f2bf(float f) {
  union { float f; unsigned u; } v; v.f = f;
  unsigned r = v.u + 0x7fffu + ((v.u >> 16) & 1u);
  return (unsigned short)(r >> 16);
}
static __device__ __forceinline__ float ldw(const void* p, long i, int fp32) {
  return fp32 ? ((const float*)p)[i] : bf2f(((const unsigned short*)p)[i]);
}
static __device__ __forceinline__ unsigned short f16b(float f) {
  return __builtin_bit_cast(unsigned short, (half_t)f);
}
static __device__ __forceinline__ h2v BC(unsigned u) {
  return __builtin_bit_cast(h2v, u);
}
static __device__ __forceinline__ float rcpf(float x) { return __builtin_amdgcn_rcpf(x); }
static __device__ __forceinline__ float sigm(float x) { return rcpf(1.f + __expf(-x)); }
static __device__ __forceinline__ float tanh_(float x) {
  float e = __expf(-2.f * fabsf(x));
  float t = (1.f - e) * rcpf(1.f + e);
  return copysignf(t, x);
}
static __device__ __forceinline__ float fdot2(h2v a, h2v b, float c) {
#if __has_builtin(__builtin_amdgcn_fdot2)
  return __builtin_amdgcn_fdot2(a, b, c, false);
#else
  return c + (float)a.x * (float)b.x + (float)a.y * (float)b.y;
#endif
}
static __device__ __forceinline__ unsigned ald(const unsigned* p) {
  return __hip_atomic_load(p, __ATOMIC_RELAXED, __HIP_MEMORY_SCOPE_AGENT);
}
static __device__ __forceinline__ unsigned vld(const unsigned* p) {
  return *(const volatile unsigned*)p;   // L1/L2 path; same-XCD fast probe
}
// Fast+safe poll: cheap L1/L2 probes, with one agent-scope (MALL) probe per
// round for guaranteed progress under any WG->XCD placement / L1 staleness.
static __device__ __forceinline__ unsigned poll_tag(const unsigned* p, unsigned tg) {
  unsigned v = vld(p);                   // B-poll timing => usually fresh hit
  if ((v >> 16) == tg) return v;
  for (;;) {
    unsigned f0 = vld(p);
    unsigned f1 = vld(p);
    unsigned a  = ald(p);
    if ((f0 >> 16) == tg) return f0;
    if ((f1 >> 16) == tg) return f1;
    if ((a  >> 16) == tg) return a;
  }
}
// Publish: fast carrier (plain store -> write-through L1 into shared XCD L2)
// + authoritative MALL copy (agent-scope exchange, R12-proven). Same value
// on both paths -> any interleaving/eviction order is benign (H1T is
// write-once; H2R slots are 64 steps apart, producer-local L2 line).
static __device__ __forceinline__ void publish(unsigned* p, unsigned val) {
  *(volatile unsigned*)p = val;
  (void)__hip_atomic_exchange(p, val, __ATOMIC_RELAXED,
                              __HIP_MEMORY_SCOPE_AGENT);
}

// ---------------------------------------------------------------- detect ----
__global__ __launch_bounds__(256) void detect(const unsigned short* __restrict__ x,
                                              int* __restrict__ flag) {
  __shared__ int cnt;
  if (threadIdx.x == 0) cnt = 0;
  __syncthreads();
  int c = 0;
#pragma unroll
  for (int i = 0; i < 8; ++i) {
    unsigned short u = x[threadIdx.x * 8 + i];
    c += (((u >> 7) & 0xFF) >= 192) ? 1 : 0;
  }
  atomicAdd(&cnt, c);
  __syncthreads();
  if (threadIdx.x == 0) *flag = (cnt > 16) ? 1 : 0;
}

// ------------------------------------------------------------------ prep ----
// task0 (y=0): Wrec packed u32 words. u = (sL*512 + tid)*128 + i, sL=L*4+s.
//   kq=tid>>8, c=tid&255, col=(c>>6)*256 + s*64 + (c&63).
//   word i -> part p=i>>6 (0=feed-forward rows 0..255, 1=recurrent rows
//   256..511), ii=i&63, rows p*256 + kq*128 + 2*ii, +1. word = lo | hi<<16.
// task1 (y=1): biases -> fp32.
// ----------------------------------------------------------------------------
__global__ __launch_bounds__(256) void prep(
    const void* __restrict__ W0, const void* __restrict__ W1,
    const void* __restrict__ b0, const void* __restrict__ b1,
    const int* __restrict__ dtf,
    unsigned* __restrict__ Wrec, float* __restrict__ bias0,
    float* __restrict__ bias1)
{
  const int fp32 = *dtf;
  int id = blockIdx.x * 256 + threadIdx.x;
  if (blockIdx.y == 0) {
    int i  = id & 127;
    int tid = (id >> 7) & 511;
    int sL = id >> 16;                 // 0..7 = L*4+s
    int L = sL >> 2, s = sL & 3;
    int kq = tid >> 8, c = tid & 255;
    int col = ((c >> 6) << 8) + s * 64 + (c & 63);
    int p  = i >> 6, ii = i & 63;
    long r0 = (long)(p * 256 + kq * 128 + 2 * ii) * 1024 + col;
    const void* W = L ? W1 : W0;
    unsigned lo = f16b(ldw(W, r0, fp32));
    unsigned hi = f16b(ldw(W, r0 + 1024, fp32));
    Wrec[id] = lo | (hi << 16);
  } else {
    if (id < 1024)       bias0[id] = ldw(b0, id, fp32);
    else if (id < 2048)  bias1[id - 1024] = ldw(b1, id - 1024, fp32);
  }
}

// ----------------------------------------------------------------- recur ----
__global__ __launch_bounds__(512) void recur(
    const void* __restrict__ x, const unsigned* __restrict__ Wrec,
    const float* __restrict__ bias0, const float* __restrict__ bias1,
    unsigned* H1T, unsigned* H2R,
    void* __restrict__ dout, const int* __restrict__ dtf)
{
  const int fp32 = *dtf;
  const int bi = blockIdx.x;
  const int L = bi >> 7, sL = bi >> 5, s = sL & 3, b = bi & 31;
  const int tid = threadIdx.x;
  const int kq = tid >> 8, c = tid & 255;
  const int abase = kq << 4;        // A-dot hbufu4 base (rows 0..255)
  const int bbase = 32 + (kq << 4); // B-dot hbufu4 base (rows 256..511)

  __shared__ __align__(16) unsigned short hbufh[512];
  __shared__ float part[2][256];
  __shared__ float bg[256];

  // ---- weights: w00-w15 feed-forward rows, w16-w31 recurrent rows ----
  const uint4* wp4 = (const uint4*)Wrec + ((size_t)sL * 512 + tid) * 32;
  uint4 w00 = wp4[0],  w01 = wp4[1],  w02 = wp4[2],  w03 = wp4[3];
  uint4 w04 = wp4[4],  w05 = wp4[5],  w06 = wp4[6],  w07 = wp4[7];
  uint4 w08 = wp4[8],  w09 = wp4[9],  w10 = wp4[10], w11 = wp4[11];
  uint4 w12 = wp4[12], w13 = wp4[13], w14 = wp4[14], w15 = wp4[15];
  uint4 w16 = wp4[16], w17 = wp4[17], w18 = wp4[18], w19 = wp4[19];
  uint4 w20 = wp4[20], w21 = wp4[21], w22 = wp4[22], w23 = wp4[23];
  uint4 w24 = wp4[24], w25 = wp4[25], w26 = wp4[26], w27 = wp4[27];
  uint4 w28 = wp4[28], w29 = wp4[29], w30 = wp4[30], w31 = wp4[31];

  if (tid < 256) {
    int scol = ((c >> 6) << 8) + s * 64 + (c & 63);
    bg[c] = (L ? bias1 : bias0)[scol];
  }

  const uint4* hbufu4 = (const uint4*)hbufh;
  float cst = 0.f;

  // ---- prologue: stage A(0), zero B (h(-1)=0), prefetch x(1) ----
  float xv = 0.f;
  if (tid < 256) {
    if (!L) {
      size_t xi = (size_t)b * 2048 * 256 + tid;
      hbufh[tid] = f16b(fp32 ? ((const float*)x)[xi]
                             : bf2f(((const unsigned short*)x)[xi]));
      size_t xj = xi + 256;  // x(1)
      xv = fp32 ? ((const float*)x)[xj] : bf2f(((const unsigned short*)x)[xj]);
    } else {
      unsigned v = poll_tag(H1T + (size_t)b * 256 + tid, 0u);
      hbufh[tid] = (unsigned short)v;
    }
  } else {
    hbufh[tid] = 0;
  }
  __syncthreads();

  for (int t = 0; t < 2048; ++t) {
    // ---- A-dot: feed-forward half, off the latency chain ----
    float a0 = 0.f, a1 = 0.f, a2 = 0.f, a3 = 0.f;
#define STEPD(BASE_, W_, J_) { uint4 hv = hbufu4[BASE_ + J_];  \
    a0 = fdot2(BC(hv.x), BC(W_.x), a0);                        \
    a1 = fdot2(BC(hv.y), BC(W_.y), a1);                        \
    a2 = fdot2(BC(hv.z), BC(W_.z), a2);                        \
    a3 = fdot2(BC(hv.w), BC(W_.w), a3); }
    STEPD(abase, w00, 0)  STEPD(abase, w01, 1)  STEPD(abase, w02, 2)  STEPD(abase, w03, 3)
    STEPD(abase, w04, 4)  STEPD(abase, w05, 5)  STEPD(abase, w06, 6)  STEPD(abase, w07, 7)
    STEPD(abase, w08, 8)  STEPD(abase, w09, 9)  STEPD(abase, w10, 10) STEPD(abase, w11, 11)
    STEPD(abase, w12, 12) STEPD(abase, w13, 13) STEPD(abase, w14, 14) STEPD(abase, w15, 15)

    // ---- poll remote h(t-1) slices, stage to B region (own slice was
    //      LDS-staged by wave0 at elem time last iteration) ----
    if (t > 0 && tid >= 256) {
      const int col = tid - 256;
      if ((col >> 6) != s) {
        const unsigned tg = (unsigned)(t - 1);
        const unsigned* pw = L
          ? H2R + ((size_t)((t - 1) & 63) * 32 + b) * 256 + col
          : H1T + ((size_t)(t - 1) * 32 + b) * 256 + col;
        hbufh[tid] = (unsigned short)poll_tag(pw, tg);
      }
    }
    __syncthreads();  // bar2: B staged; A region now safe to rewrite

    // ---- B-dot: recurrent half (the only dot on the serial chain) ----
    STEPD(bbase, w16, 0)  STEPD(bbase, w17, 1)  STEPD(bbase, w18, 2)  STEPD(bbase, w19, 3)
    STEPD(bbase, w20, 4)  STEPD(bbase, w21, 5)  STEPD(bbase, w22, 6)  STEPD(bbase, w23, 7)
    STEPD(bbase, w24, 8)  STEPD(bbase, w25, 9)  STEPD(bbase, w26, 10) STEPD(bbase, w27, 11)
    STEPD(bbase, w28, 12) STEPD(bbase, w29, 13) STEPD(bbase, w30, 14) STEPD(bbase, w31, 15)
#undef STEPD
    part[kq][c] = (a0 + a1) + (a2 + a3);

    // ---- stage A(t+1) under the elementwise shadow ----
    if (t < 2047 && tid < 256) {
      if (!L) {
        hbufh[tid] = f16b(xv);
        if (t + 2 < 2048) {
          size_t xi = ((size_t)b * 2048 + (t + 2)) * 256 + tid;
          xv = fp32 ? ((const float*)x)[xi]
                    : bf2f(((const unsigned short*)x)[xi]);
        }
      } else {
        unsigned v = poll_tag(H1T + ((size_t)(t + 1) * 32 + b) * 256 + tid,
                              (unsigned)(t + 1));
        hbufh[tid] = (unsigned short)v;
      }
    }
    __syncthreads();  // bar3: part + A(t+1) staged

    // ---- elementwise + publish (wave 0); gate order (i, j, f, o) ----
    if (tid < 64) {
      int j = tid;
      float gi = part[0][j]       + part[1][j]       + bg[j];
      float gj = part[0][64 + j]  + part[1][64 + j]  + bg[64 + j];
      float gf = part[0][128 + j] + part[1][128 + j] + bg[128 + j];
      float go = part[0][192 + j] + part[1][192 + j] + bg[192 + j];
      float cn = cst * sigm(gf + 1.f) + sigm(gi) * tanh_(gj);
      cst = cn;
      float h = tanh_(cn) * sigm(go);
      unsigned short hb = f16b(h);
      unsigned val = ((unsigned)t << 16) | (unsigned)hb;
      // own-slice columns straight into next step's LDS B region
      hbufh[256 + (s << 6) + j] = hb;
      if (!L) {
        publish(H1T + ((size_t)t * 32 + b) * 256 + s * 64 + j, val);
      } else {
        publish(H2R + ((size_t)(t & 63) * 32 + b) * 256 + s * 64 + j, val);
        size_t oi = ((size_t)b * 2048 + t) * 256 + s * 64 + j;
        if (fp32) ((float*)dout)[oi] = h;
        else      ((unsigned short*)dout)[oi] = f2bf(h);
      }
    }
    // no trailing barrier: next iter's A-dot reads A region (staged before
    // bar3); B staging (next iter) is after this thread's bar3; part rewrite
    // (next iter) is after bar2(t+1), which wave0 reaches only after its
    // elementwise reads complete.
  }
}

// ----------------------------------------------------------------------------
extern "C" void kernel_launch(void* const* d_in, const int* in_sizes, int n_in,
                              void* d_out, int out_size, void* d_ws, size_t ws_size,
                              hipStream_t stream) {
  const void* x  = d_in[0];   // [32][2048][256]
  const void* W0 = d_in[1];   // [512][1024]
  const void* b0 = d_in[2];   // [1024]
  const void* W1 = d_in[3];   // [512][1024]
  const void* b1 = d_in[4];   // [1024]

  char* p = (char*)d_ws;                                   // ~71.3 MB total
  unsigned* Wrec = (unsigned*)p; p += (size_t)524288 * 4;  // 2 MB packed f16x2
  unsigned* H1T  = (unsigned*)p; p += (size_t)2048 * 32 * 256 * 4;  // 67.1 MB
  unsigned* H2R  = (unsigned*)p; p += (size_t)64 * 32 * 256 * 4;    // 2 MB ring
  float* bias0   = (float*)p;    p += 4096;
  float* bias1   = (float*)p;    p += 4096;
  int* dflag     = (int*)p;      p += 256;

  detect<<<1, 256, 0, stream>>>((const unsigned short*)x, dflag);
  prep<<<dim3(2048, 2), 256, 0, stream>>>(W0, W1, b0, b1, dflag,
                                          Wrec, bias0, bias1);
  recur<<<256, 512, 0, stream>>>(x, Wrec, bias0, bias1,
                                 H1T, H2R, d_out, dflag);
}

// Round 9
// 3136.103 us; speedup vs baseline: 1.2757x; 1.2757x over previous
//
#include <hip/hip_runtime.h>
#include <hip/hip_bf16.h>
#include <hip/hip_fp16.h>

// ============================================================================
// 2-layer LSTM (TF BasicLSTMCell, forget_bias=1), B=32, T=2048, D=H=256.
// R14: R12 (best: 3159us) + ONE change: ~128cy s_sleep before the B-poll's
//   first probe, so the first MALL sample lands AFTER publish visibility.
//   Timing model (RT~900cy, visibility~450cy): pollers clear bar3 ~300cy
//   before wave0's publish (elem runs post-bar3), spend ~300cy on the A-dot,
//   and issue the first agent probe at ~Tp+0 -> it samples MALL at ~Tp+450,
//   exactly at the visibility edge -> ~50% miss, and a miss costs 2 RTs
//   (detect + reissue) ~= +900cy. Sleeping ~128cy moves the sample to
//   ~Tp+580+ -> deterministic first-probe hit, discovery ~= issue+RT.
//   Closed families (measured): L2 fast probes — asm sc0 (R8/R9 crash),
//   WG-scope CAS (R10: +28%, RMW dirties lines), volatile load (R13: stale
//   L1, +27%); publish-side atomicExch (R12: null => visibility prompt);
//   reg pinning (R6), on-chain dot halving (R7), batch interleave (R11).
//   Unchanged from R12: 256 WGs = 2L x 4slice x 32batch, 512 thr; A/B split
//   dot (A off-chain); x(t+1) prefetch; 4-outstanding agent-scope poll;
//   tagged words (t<<16|f16, poison-safe); wave0 own-slice LDS self-stage;
//   H1 write-once trace; H2 depth-4 ring; atomicExch publish; prep; detect.
// ============================================================================

typedef _Float16 half_t;
typedef __attribute__((ext_vector_type(2))) _Float16 h2v;

static __device__ __forceinline__ float bf2f(unsigned short u) {
  union { unsigned u; float f; } v; v.u = ((unsigned)u) << 16; return v.f;
}
static __device__ __forceinline__ unsigned short f2bf(float f) {
  union { float f; unsigned u; } v; v.f = f;
  unsigned r = v.u + 0x7fffu + ((v.u >> 16) & 1u);
  return (unsigned short)(r >> 16);
}
static __device__ __forceinline__ float ldw(const void* p, long i, int fp32) {
  return fp32 ? ((const float*)p)[i] : bf2f(((const unsigned short*)p)[i]);
}
static __device__ __forceinline__ unsigned short f16b(float f) {
  return __builtin_bit_cast(unsigned short, (half_t)f);
}
static __device__ __forceinline__ h2v BC(unsigned u) {
  return __builtin_bit_cast(h2v, u);
}
static __device__ __forceinline__ float rcpf(float x) { return __builtin_amdgcn_rcpf(x); }
static __device__ __forceinline__ float sigm(float x) { return rcpf(1.f + __expf(-x)); }
static __device__ __forceinline__ float tanh_(float x) {
  float e = __expf(-2.f * fabsf(x));
  float t = (1.f - e) * rcpf(1.f + e);
  return copysignf(t, x);
}
static __device__ __forceinline__ float fdot2(h2v a, h2v b, float c) {
#if __has_builtin(__builtin_amdgcn_fdot2)
  return __builtin_amdgcn_fdot2(a, b, c, false);
#else
  return c + (float)a.x * (float)b.x + (float)a.y * (float)b.y;
#endif
}
static __device__ __forceinline__ unsigned ald(const unsigned* p) {
  return __hip_atomic_load(p, __ATOMIC_RELAXED, __HIP_MEMORY_SCOPE_AGENT);
}
// 4-deep pipelined tag poll: 4 outstanding loads per round, staggered checks.
static __device__ __forceinline__ unsigned poll_tag(const unsigned* p, unsigned tg) {
  unsigned v = ald(p);
  while ((v >> 16) != tg) {
    unsigned a = ald(p);
    unsigned b = ald(p);
    unsigned c = ald(p);
    unsigned d = ald(p);
    if ((a >> 16) == tg) { v = a; break; }
    if ((b >> 16) == tg) { v = b; break; }
    if ((c >> 16) == tg) { v = c; break; }
    v = d;
  }
  return v;
}
// Publish at the coherence point (R12-proven, neutral-to-slightly-better).
static __device__ __forceinline__ void publish(unsigned* p, unsigned val) {
  (void)__hip_atomic_exchange(p, val, __ATOMIC_RELAXED,
                              __HIP_MEMORY_SCOPE_AGENT);
}

// ---------------------------------------------------------------- detect ----
__global__ __launch_bounds__(256) void detect(const unsigned short* __restrict__ x,
                                              int* __restrict__ flag) {
  __shared__ int cnt;
  if (threadIdx.x == 0) cnt = 0;
  __syncthreads();
  int c = 0;
#pragma unroll
  for (int i = 0; i < 8; ++i) {
    unsigned short u = x[threadIdx.x * 8 + i];
    c += (((u >> 7) & 0xFF) >= 192) ? 1 : 0;
  }
  atomicAdd(&cnt, c);
  __syncthreads();
  if (threadIdx.x == 0) *flag = (cnt > 16) ? 1 : 0;
}

// ------------------------------------------------------------------ prep ----
// task0 (y=0): Wrec packed u32 words. u = (sL*512 + tid)*128 + i, sL=L*4+s.
//   kq=tid>>8, c=tid&255, col=(c>>6)*256 + s*64 + (c&63).
//   word i -> part p=i>>6 (0=feed-forward rows 0..255, 1=recurrent rows
//   256..511), ii=i&63, rows p*256 + kq*128 + 2*ii, +1. word = lo | hi<<16.
// task1 (y=1): biases -> fp32.
// ----------------------------------------------------------------------------
__global__ __launch_bounds__(256) void prep(
    const void* __restrict__ W0, const void* __restrict__ W1,
    const void* __restrict__ b0, const void* __restrict__ b1,
    const int* __restrict__ dtf,
    unsigned* __restrict__ Wrec, float* __restrict__ bias0,
    float* __restrict__ bias1)
{
  const int fp32 = *dtf;
  int id = blockIdx.x * 256 + threadIdx.x;
  if (blockIdx.y == 0) {
    int i  = id & 127;
    int tid = (id >> 7) & 511;
    int sL = id >> 16;                 // 0..7 = L*4+s
    int L = sL >> 2, s = sL & 3;
    int kq = tid >> 8, c = tid & 255;
    int col = ((c >> 6) << 8) + s * 64 + (c & 63);
    int p  = i >> 6, ii = i & 63;
    long r0 = (long)(p * 256 + kq * 128 + 2 * ii) * 1024 + col;
    const void* W = L ? W1 : W0;
    unsigned lo = f16b(ldw(W, r0, fp32));
    unsigned hi = f16b(ldw(W, r0 + 1024, fp32));
    Wrec[id] = lo | (hi << 16);
  } else {
    if (id < 1024)       bias0[id] = ldw(b0, id, fp32);
    else if (id < 2048)  bias1[id - 1024] = ldw(b1, id - 1024, fp32);
  }
}

// ----------------------------------------------------------------- recur ----
__global__ __launch_bounds__(512) void recur(
    const void* __restrict__ x, const unsigned* __restrict__ Wrec,
    const float* __restrict__ bias0, const float* __restrict__ bias1,
    unsigned* H1T, unsigned* H2R,
    void* __restrict__ dout, const int* __restrict__ dtf)
{
  const int fp32 = *dtf;
  const int bi = blockIdx.x;
  const int L = bi >> 7, sL = bi >> 5, s = sL & 3, b = bi & 31;
  const int tid = threadIdx.x;
  const int kq = tid >> 8, c = tid & 255;
  const int abase = kq << 4;        // A-dot hbufu4 base (rows 0..255)
  const int bbase = 32 + (kq << 4); // B-dot hbufu4 base (rows 256..511)

  __shared__ __align__(16) unsigned short hbufh[512];
  __shared__ float part[2][256];
  __shared__ float bg[256];

  // ---- weights: w00-w15 feed-forward rows, w16-w31 recurrent rows ----
  const uint4* wp4 = (const uint4*)Wrec + ((size_t)sL * 512 + tid) * 32;
  uint4 w00 = wp4[0],  w01 = wp4[1],  w02 = wp4[2],  w03 = wp4[3];
  uint4 w04 = wp4[4],  w05 = wp4[5],  w06 = wp4[6],  w07 = wp4[7];
  uint4 w08 = wp4[8],  w09 = wp4[9],  w10 = wp4[10], w11 = wp4[11];
  uint4 w12 = wp4[12], w13 = wp4[13], w14 = wp4[14], w15 = wp4[15];
  uint4 w16 = wp4[16], w17 = wp4[17], w18 = wp4[18], w19 = wp4[19];
  uint4 w20 = wp4[20], w21 = wp4[21], w22 = wp4[22], w23 = wp4[23];
  uint4 w24 = wp4[24], w25 = wp4[25], w26 = wp4[26], w27 = wp4[27];
  uint4 w28 = wp4[28], w29 = wp4[29], w30 = wp4[30], w31 = wp4[31];

  if (tid < 256) {
    int scol = ((c >> 6) << 8) + s * 64 + (c & 63);
    bg[c] = (L ? bias1 : bias0)[scol];
  }

  const uint4* hbufu4 = (const uint4*)hbufh;
  float cst = 0.f;

  // ---- prologue: stage A(0), zero B (h(-1)=0), prefetch x(1) ----
  float xv = 0.f;
  if (tid < 256) {
    if (!L) {
      size_t xi = (size_t)b * 2048 * 256 + tid;
      hbufh[tid] = f16b(fp32 ? ((const float*)x)[xi]
                             : bf2f(((const unsigned short*)x)[xi]));
      size_t xj = xi + 256;  // x(1)
      xv = fp32 ? ((const float*)x)[xj] : bf2f(((const unsigned short*)x)[xj]);
    } else {
      unsigned v = poll_tag(H1T + (size_t)b * 256 + tid, 0u);
      hbufh[tid] = (unsigned short)v;
    }
  } else {
    hbufh[tid] = 0;
  }
  __syncthreads();

  for (int t = 0; t < 2048; ++t) {
    // ---- A-dot: feed-forward half, off the latency chain ----
    float a0 = 0.f, a1 = 0.f, a2 = 0.f, a3 = 0.f;
#define STEPD(BASE_, W_, J_) { uint4 hv = hbufu4[BASE_ + J_];  \
    a0 = fdot2(BC(hv.x), BC(W_.x), a0);                        \
    a1 = fdot2(BC(hv.y), BC(W_.y), a1);                        \
    a2 = fdot2(BC(hv.z), BC(W_.z), a2);                        \
    a3 = fdot2(BC(hv.w), BC(W_.w), a3); }
    STEPD(abase, w00, 0)  STEPD(abase, w01, 1)  STEPD(abase, w02, 2)  STEPD(abase, w03, 3)
    STEPD(abase, w04, 4)  STEPD(abase, w05, 5)  STEPD(abase, w06, 6)  STEPD(abase, w07, 7)
    STEPD(abase, w08, 8)  STEPD(abase, w09, 9)  STEPD(abase, w10, 10) STEPD(abase, w11, 11)
    STEPD(abase, w12, 12) STEPD(abase, w13, 13) STEPD(abase, w14, 14) STEPD(abase, w15, 15)

    // ---- poll remote h(t-1) slices, stage to B region (own slice was
    //      LDS-staged by wave0 at elem time last iteration).
    //      s_sleep(2) ~128cy first: shifts the first MALL sample past the
    //      producers' publish-visibility edge -> deterministic first hit.
    //      Branch is wave-uniform (col>>6 constant per wave). ----
    if (t > 0 && tid >= 256) {
      const int col = tid - 256;
      if ((col >> 6) != s) {
        __builtin_amdgcn_s_sleep(2);
        const unsigned tg = (unsigned)(t - 1);
        const unsigned* pw = L
          ? H2R + ((size_t)((t - 1) & 3) * 32 + b) * 256 + col
          : H1T + ((size_t)(t - 1) * 32 + b) * 256 + col;
        hbufh[tid] = (unsigned short)poll_tag(pw, tg);
      }
    }
    __syncthreads();  // bar2: B staged; A region now safe to rewrite

    // ---- B-dot: recurrent half (the only dot on the serial chain) ----
    STEPD(bbase, w16, 0)  STEPD(bbase, w17, 1)  STEPD(bbase, w18, 2)  STEPD(bbase, w19, 3)
    STEPD(bbase, w20, 4)  STEPD(bbase, w21, 5)  STEPD(bbase, w22, 6)  STEPD(bbase, w23, 7)
    STEPD(bbase, w24, 8)  STEPD(bbase, w25, 9)  STEPD(bbase, w26, 10) STEPD(bbase, w27, 11)
    STEPD(bbase, w28, 12) STEPD(bbase, w29, 13) STEPD(bbase, w30, 14) STEPD(bbase, w31, 15)
#undef STEPD
    part[kq][c] = (a0 + a1) + (a2 + a3);

    // ---- stage A(t+1) under the elementwise shadow ----
    if (t < 2047 && tid < 256) {
      if (!L) {
        hbufh[tid] = f16b(xv);
        if (t + 2 < 2048) {
          size_t xi = ((size_t)b * 2048 + (t + 2)) * 256 + tid;
          xv = fp32 ? ((const float*)x)[xi]
                    : bf2f(((const unsigned short*)x)[xi]);
        }
      } else {
        unsigned v = poll_tag(H1T + ((size_t)(t + 1) * 32 + b) * 256 + tid,
                              (unsigned)(t + 1));
        hbufh[tid] = (unsigned short)v;
      }
    }
    __syncthreads();  // bar3: part + A(t+1) staged

    // ---- elementwise + publish (wave 0); gate order (i, j, f, o) ----
    if (tid < 64) {
      int j = tid;
      float gi = part[0][j]       + part[1][j]       + bg[j];
      float gj = part[0][64 + j]  + part[1][64 + j]  + bg[64 + j];
      float gf = part[0][128 + j] + part[1][128 + j] + bg[128 + j];
      float go = part[0][192 + j] + part[1][192 + j] + bg[192 + j];
      float cn = cst * sigm(gf + 1.f) + sigm(gi) * tanh_(gj);
      cst = cn;
      float h = tanh_(cn) * sigm(go);
      unsigned short hb = f16b(h);
      unsigned val = ((unsigned)t << 16) | (unsigned)hb;
      // own-slice columns straight into next step's LDS B region
      hbufh[256 + (s << 6) + j] = hb;
      if (!L) {
        publish(H1T + ((size_t)t * 32 + b) * 256 + s * 64 + j, val);
      } else {
        publish(H2R + ((size_t)(t & 3) * 32 + b) * 256 + s * 64 + j, val);
        size_t oi = ((size_t)b * 2048 + t) * 256 + s * 64 + j;
        if (fp32) ((float*)dout)[oi] = h;
        else      ((unsigned short*)dout)[oi] = f2bf(h);
      }
    }
    // no trailing barrier: next iter's A-dot reads A region (staged before
    // bar3); B staging (next iter) is after this thread's bar3; part rewrite
    // (next iter) is after bar2(t+1), which wave0 reaches only after its
    // elementwise reads complete.
  }
}

// ----------------------------------------------------------------------------
extern "C" void kernel_launch(void* const* d_in, const int* in_sizes, int n_in,
                              void* d_out, int out_size, void* d_ws, size_t ws_size,
                              hipStream_t stream) {
  const void* x  = d_in[0];   // [32][2048][256]
  const void* W0 = d_in[1];   // [512][1024]
  const void* b0 = d_in[2];   // [1024]
  const void* W1 = d_in[3];   // [512][1024]
  const void* b1 = d_in[4];   // [1024]

  char* p = (char*)d_ws;                                   // ~69.3 MB total
  unsigned* Wrec = (unsigned*)p; p += (size_t)524288 * 4;  // 2 MB packed f16x2
  unsigned* H1T  = (unsigned*)p; p += (size_t)2048 * 32 * 256 * 4;  // 67.1 MB
  unsigned* H2R  = (unsigned*)p; p += (size_t)4 * 32 * 256 * 4;     // 128 KB
  float* bias0   = (float*)p;    p += 4096;
  float* bias1   = (float*)p;    p += 4096;
  int* dflag     = (int*)p;      p += 256;

  detect<<<1, 256, 0, stream>>>((const unsigned short*)x, dflag);
  prep<<<dim3(2048, 2), 256, 0, stream>>>(W0, W1, b0, b1, dflag,
                                          Wrec, bias0, bias1);
  recur<<<256, 512, 0, stream>>>(x, Wrec, bias0, bias1,
                                 H1T, H2R, d_out, dflag);
}